// Round 5
// baseline (551.270 us; speedup 1.0000x reference)
//
#include <hip/hip_runtime.h>
#include <math.h>

#define B_ 2
#define P_ 16384
#define C_ 5
#define S_ 4096
#define KNN_ 8
#define L_ 64

typedef unsigned short u16;
typedef unsigned int u32;

// ---- static scratch: fully rewritten every call before any read ----
__device__ int   g_f32x, g_f32w;               // dtype flags (1 = float32)
__device__ float g_mnmx[16];
__device__ int   g_idx0[B_ * S_];
__device__ int   g_idxk[B_ * KNN_ * S_];
__device__ float g_partials[256 * 128];
__device__ float g_stats[128];

__device__ __forceinline__ float bf2f(u16 u) {
  union { u32 i; float f; } c; c.i = ((u32)u) << 16; return c.f;
}
__device__ __forceinline__ u16 f2bf(float f) {
  union { float f; u32 i; } c; c.f = f;
  u32 r = c.i + 0x7fffu + ((c.i >> 16) & 1u);
  return (u16)(r >> 16);
}
// dtype-agnostic scalar load
__device__ __forceinline__ float ldany(const void* p, int i, int f32) {
  return f32 ? ((const float*)p)[i] : bf2f(((const u16*)p)[i]);
}

// ---------------- dtype detector ----------------
// Genuine bf16 gaussian data: every value finite, |v| < 1024.
// f32 data read as bf16: low-half u16s have uniform exponent bits -> huge/NaN values w.p. ~1.
__device__ __forceinline__ int chk_bad(const void* p, int n, int tid) {
  int bad = 0;
  for (int i = tid; i < n; i += 256) {
    float f = bf2f(((const u16*)p)[i]);
    if (!(f == f) || fabsf(f) > 1024.0f) bad = 1;
  }
  return bad;
}
__global__ __launch_bounds__(256) void k_detect(const void* x, const void* wpos,
                                                const void* wconv, const void* wa1,
                                                const void* wa2, const void* wb1,
                                                const void* wb2) {
  __shared__ int sx, sw;
  int tid = threadIdx.x;
  if (tid == 0) { sx = 0; sw = 0; }
  __syncthreads();
  int bx = chk_bad(x, 1024, tid);
  int bw = chk_bad(wpos, 320, tid) | chk_bad(wconv, 128, tid) | chk_bad(wa1, 2048, tid)
         | chk_bad(wa2, 32, tid)   | chk_bad(wb1, 4096, tid)  | chk_bad(wb2, 256, tid);
  if (bx) atomicOr(&sx, 1);
  if (bw) atomicOr(&sw, 1);
  __syncthreads();
  if (tid == 0) { g_f32x = sx; g_f32w = sw; }
}

// ---------------- min/max over P for channels 0,1 ----------------
__global__ __launch_bounds__(256) void k_minmax(const void* __restrict__ x) {
  int f32 = g_f32x;
  int bc = blockIdx.x;            // 0..3 : b*2 + ch
  int b = bc >> 1, ch = bc & 1;
  int base = (b * C_ + ch) * P_;
  float mn = INFINITY, mx = -INFINITY;
  for (int p = threadIdx.x; p < P_; p += 256) {
    float v = ldany(x, base + p, f32);
    mn = fminf(mn, v); mx = fmaxf(mx, v);
  }
  for (int off = 32; off; off >>= 1) {
    mn = fminf(mn, __shfl_down(mn, off));
    mx = fmaxf(mx, __shfl_down(mx, off));
  }
  __shared__ float smn[4], smx[4];
  int wid = threadIdx.x >> 6;
  if ((threadIdx.x & 63) == 0) { smn[wid] = mn; smx[wid] = mx; }
  __syncthreads();
  if (threadIdx.x == 0) {
    for (int w = 1; w < 4; ++w) { mn = fminf(mn, smn[w]); mx = fmaxf(mx, smx[w]); }
    g_mnmx[bc * 2] = mn; g_mnmx[bc * 2 + 1] = mx;
  }
}

// ---------------- kNN #1 : nearest of 16384 2D points per grid query ----------------
// contraction-free f32, np association order
template<int F32>
__device__ __forceinline__ void knn1_impl(const void* __restrict__ xv) {
  int bi = blockIdx.x;
  int b = bi >> 12, s = bi & (S_ - 1);
  float mn0 = g_mnmx[(b * 2 + 0) * 2], mx0 = g_mnmx[(b * 2 + 0) * 2 + 1];
  float mn1 = g_mnmx[(b * 2 + 1) * 2], mx1 = g_mnmx[(b * 2 + 1) * 2 + 1];
  float mm0 = (float)(s & (L_ - 1)) * 0.015625f;
  float mm1 = (float)(s >> 6) * 0.015625f;
  float ps0 = __fadd_rn(__fmul_rn(mm0, __fsub_rn(mx0, mn0)), mn0);
  float ps1 = __fadd_rn(__fmul_rn(mm1, __fsub_rn(mx1, mn1)), mn1);
  float xx2 = __fadd_rn(__fmul_rn(ps0, ps0), __fmul_rn(ps1, ps1));
  int base0 = b * C_ * P_, base1 = base0 + P_;
  float best = -INFINITY; int bestp = 0;
  for (int p = threadIdx.x; p < P_; p += 256) {
    float a0 = F32 ? ((const float*)xv)[base0 + p] : bf2f(((const u16*)xv)[base0 + p]);
    float a1 = F32 ? ((const float*)xv)[base1 + p] : bf2f(((const u16*)xv)[base1 + p]);
    float dot = __fadd_rn(__fmul_rn(a0, ps0), __fmul_rn(a1, ps1));
    float inner = __fmul_rn(-2.0f, dot);
    float xx = __fadd_rn(__fmul_rn(a0, a0), __fmul_rn(a1, a1));
    float d = __fsub_rn(__fsub_rn(-xx, inner), xx2);
    if (d > best) { best = d; bestp = p; }   // strict > keeps lowest idx on ties
  }
  for (int off = 32; off; off >>= 1) {
    float ov = __shfl_down(best, off); int op = __shfl_down(bestp, off);
    if (ov > best || (ov == best && op < bestp)) { best = ov; bestp = op; }
  }
  __shared__ float sv[4]; __shared__ int sp2[4];
  int wid = threadIdx.x >> 6;
  if ((threadIdx.x & 63) == 0) { sv[wid] = best; sp2[wid] = bestp; }
  __syncthreads();
  if (threadIdx.x == 0) {
    for (int w = 1; w < 4; ++w)
      if (sv[w] > best || (sv[w] == best && sp2[w] < bestp)) { best = sv[w]; bestp = sp2[w]; }
    g_idx0[b * S_ + s] = bestp;
  }
}
__global__ __launch_bounds__(256) void k_knn1(const void* __restrict__ x) {
  if (g_f32x) knn1_impl<1>(x); else knn1_impl<0>(x);
}

// ---------------- kNN #2 : top-8 of 16384 3D points per sampled query ----------------
template<int F32>
__device__ __forceinline__ void knn2_impl(const void* __restrict__ xv) {
  int bi = blockIdx.x;
  int b = bi >> 12, s = bi & (S_ - 1);
  int base0 = b * C_ * P_, base1 = base0 + P_, base2 = base1 + P_;
  int q = g_idx0[b * S_ + s] & (P_ - 1);
  float q0 = F32 ? ((const float*)xv)[base0 + q] : bf2f(((const u16*)xv)[base0 + q]);
  float q1 = F32 ? ((const float*)xv)[base1 + q] : bf2f(((const u16*)xv)[base1 + q]);
  float q2 = F32 ? ((const float*)xv)[base2 + q] : bf2f(((const u16*)xv)[base2 + q]);
  float xx2 = __fadd_rn(__fadd_rn(__fmul_rn(q0, q0), __fmul_rn(q1, q1)), __fmul_rn(q2, q2));
  float tv[8]; int ti[8];
#pragma unroll
  for (int k = 0; k < 8; ++k) { tv[k] = -INFINITY; ti[k] = 0x7fffffff; }
  for (int p = threadIdx.x; p < P_; p += 256) {
    float a0 = F32 ? ((const float*)xv)[base0 + p] : bf2f(((const u16*)xv)[base0 + p]);
    float a1 = F32 ? ((const float*)xv)[base1 + p] : bf2f(((const u16*)xv)[base1 + p]);
    float a2 = F32 ? ((const float*)xv)[base2 + p] : bf2f(((const u16*)xv)[base2 + p]);
    float dot = __fadd_rn(__fadd_rn(__fmul_rn(a0, q0), __fmul_rn(a1, q1)), __fmul_rn(a2, q2));
    float inner = __fmul_rn(-2.0f, dot);
    float xx = __fadd_rn(__fadd_rn(__fmul_rn(a0, a0), __fmul_rn(a1, a1)), __fmul_rn(a2, a2));
    float d = __fsub_rn(__fsub_rn(-xx, inner), xx2);
    if (d > tv[7]) {
      float v = d; int ix = p;
#pragma unroll
      for (int k = 0; k < 8; ++k) {  // sorted insert (val desc, idx asc)
        bool sw = (v > tv[k]) || (v == tv[k] && ix < ti[k]);
        float ov = tv[k]; int oi = ti[k];
        tv[k] = sw ? v : tv[k]; ti[k] = sw ? ix : ti[k];
        v = sw ? ov : v;        ix = sw ? oi : ix;
      }
    }
  }
  __shared__ float swv[4]; __shared__ int swp[4];
  __shared__ int bwp_s;
  for (int r = 0; r < 8; ++r) {
    float v = tv[0]; int pi = ti[0];
    for (int off = 32; off; off >>= 1) {
      float ov = __shfl_down(v, off); int op = __shfl_down(pi, off);
      if (ov > v || (ov == v && op < pi)) { v = ov; pi = op; }
    }
    if ((threadIdx.x & 63) == 0) { swv[threadIdx.x >> 6] = v; swp[threadIdx.x >> 6] = pi; }
    __syncthreads();
    if (threadIdx.x == 0) {
      for (int w = 1; w < 4; ++w)
        if (swv[w] > v || (swv[w] == v && swp[w] < pi)) { v = swv[w]; pi = swp[w]; }
      bwp_s = pi;
      g_idxk[b * (KNN_ * S_) + r * S_ + s] = pi;   // rank-major (B,k,s) like ref
    }
    __syncthreads();
    int wp = bwp_s;
    if (ti[0] == wp) {              // candidate idx unique per thread
#pragma unroll
      for (int k = 0; k < 7; ++k) { tv[k] = tv[k + 1]; ti[k] = ti[k + 1]; }
      tv[7] = -INFINITY; ti[7] = 0x7fffffff;
    }
  }
}
__global__ __launch_bounds__(256) void k_knn2(const void* __restrict__ x) {
  if (g_f32x) knn2_impl<1>(x); else knn2_impl<0>(x);
}

// ---------------- helper: gather + the two matvecs for one element ----------------
__device__ __forceinline__ void elem_vals(const void* xv, int xf32, int xbase,
                                          const int* fb, int n,
                                          const float* sWpos, const float* sbpos,
                                          const float* sWconv, const float* sbconv,
                                          float* val /*[64]*/) {
  int p = fb[n] & (P_ - 1);
  int p0 = fb[n & ~7] & (P_ - 1);           // j=0 slot of same group
  float xvv[4];
#pragma unroll
  for (int c = 0; c < 4; ++c) xvv[c] = ldany(xv, xbase + c * P_ + p, xf32);
  float pc[3];
#pragma unroll
  for (int c = 0; c < 3; ++c) pc[c] = ldany(xv, xbase + c * P_ + p0, xf32);
  float d0 = xvv[0] - pc[0], d1 = xvv[1] - pc[1], d2 = xvv[2] - pc[2];
  float sq = d0 * d0 + d1 * d1 + d2 * d2;
  float temp = (sq > 0.0f) ? sqrtf(sq) : 0.0f;
  float pe[10] = {xvv[0], xvv[1], xvv[2], pc[0], pc[1], pc[2], d0, d1, d2, temp};
#pragma unroll
  for (int o = 0; o < 32; ++o) {            // val[0..31] = conv branch
    float acc = sbconv[o];
#pragma unroll
    for (int c = 0; c < 4; ++c) acc = fmaf(sWconv[o * 4 + c], xvv[c], acc);
    val[o] = acc;
  }
#pragma unroll
  for (int o = 0; o < 32; ++o) {            // val[32..63] = pos branch
    float acc = sbpos[o];
#pragma unroll
    for (int c = 0; c < 10; ++c) acc = fmaf(sWpos[o * 10 + c], pe[c], acc);
    val[32 + o] = acc;
  }
}

// ---------------- BN partial sums ----------------
__global__ __launch_bounds__(256) void k_partial(const void* __restrict__ x,
                                                 const void* __restrict__ Wpos,
                                                 const void* __restrict__ bpos,
                                                 const void* __restrict__ Wconv,
                                                 const void* __restrict__ bconv) {
  __shared__ float sWpos[320], sbpos[32], sWconv[128], sbconv[32];
  __shared__ float sacc[4][128];
  int tid = threadIdx.x;
  int xf32 = g_f32x, wf32 = g_f32w;
  for (int i2 = tid; i2 < 320; i2 += 256) sWpos[i2] = ldany(Wpos, i2, wf32);
  if (tid < 128) sWconv[tid] = ldany(Wconv, tid, wf32);
  if (tid < 32) { sbpos[tid] = ldany(bpos, tid, wf32); sbconv[tid] = ldany(bconv, tid, wf32); }
  __syncthreads();
  int t = blockIdx.x * 256 + tid;          // < 65536
  int b = t >> 15, n = t & 32767;
  const int* fb = g_idxk + b * 32768;
  float val[64];
  elem_vals(x, xf32, b * C_ * P_, fb, n, sWpos, sbpos, sWconv, sbconv, val);
  int wid = tid >> 6, lane = tid & 63;
#pragma unroll
  for (int c = 0; c < 64; ++c) {
    float s = val[c], q = val[c] * val[c];
    for (int off = 32; off; off >>= 1) {
      s += __shfl_down(s, off);
      q += __shfl_down(q, off);
    }
    if (lane == 0) { sacc[wid][c * 2] = s; sacc[wid][c * 2 + 1] = q; }
  }
  __syncthreads();
  if (tid < 128) {
    g_partials[blockIdx.x * 128 + tid] =
        sacc[0][tid] + sacc[1][tid] + sacc[2][tid] + sacc[3][tid];
  }
}

// ---------------- finalize BN stats ----------------
__global__ void k_finalize(const void* __restrict__ g1, const void* __restrict__ be1,
                           const void* __restrict__ g2, const void* __restrict__ be2) {
  int ch = threadIdx.x;                    // blockDim = 64
  if (ch >= 64) return;
  int wf32 = g_f32w;
  float sum = 0.f, sq = 0.f;
  for (int blk = 0; blk < 256; ++blk) {
    sum += g_partials[blk * 128 + ch * 2];
    sq  += g_partials[blk * 128 + ch * 2 + 1];
  }
  float mean = sum * (1.0f / 65536.0f);
  float var = sq * (1.0f / 65536.0f) - mean * mean;
  int o = ch & 31;
  float g  = ldany(ch < 32 ? g1 : g2, o, wf32);
  float be = ldany(ch < 32 ? be1 : be2, o, wf32);
  float scale = g / sqrtf(var + 1e-5f);
  g_stats[ch * 2] = scale;
  g_stats[ch * 2 + 1] = be - mean * scale;
}

// ---------------- pass 2 : recompute + BN + attention + output ----------------
__global__ __launch_bounds__(256) void k_pass2(const void* __restrict__ x,
                                               const void* __restrict__ Wpos,
                                               const void* __restrict__ bpos,
                                               const void* __restrict__ Wconv,
                                               const void* __restrict__ bconv,
                                               const void* __restrict__ Wa1,
                                               const void* __restrict__ ba1,
                                               const void* __restrict__ Wa2,
                                               const void* __restrict__ ba2,
                                               const void* __restrict__ Wb1,
                                               const void* __restrict__ bb1,
                                               const void* __restrict__ Wb2,
                                               const void* __restrict__ bb2,
                                               void* __restrict__ out) {
  __shared__ float sWpos[320], sbpos[32], sWconv[128], sbconv[32];
  __shared__ float sWa1[2048], sba1[32], sWa2[32];
  __shared__ float sWb1[64 * 65];
  __shared__ float sbb1[64], sWb2[256], sbb2[64], sstats[128];
  __shared__ float sba2;
  int tid = threadIdx.x;
  int xf32 = g_f32x, wf32 = g_f32w;
  for (int i2 = tid; i2 < 320; i2 += 256) sWpos[i2] = ldany(Wpos, i2, wf32);
  if (tid < 128) sWconv[tid] = ldany(Wconv, tid, wf32);
  if (tid < 32) { sbpos[tid] = ldany(bpos, tid, wf32); sbconv[tid] = ldany(bconv, tid, wf32); }
  for (int i2 = tid; i2 < 2048; i2 += 256) sWa1[i2] = ldany(Wa1, i2, wf32);
  for (int i2 = tid; i2 < 4096; i2 += 256) sWb1[(i2 >> 6) * 65 + (i2 & 63)] = ldany(Wb1, i2, wf32);
  if (tid >= 32 && tid < 64) { sba1[tid - 32] = ldany(ba1, tid - 32, wf32); sWa2[tid - 32] = ldany(Wa2, tid - 32, wf32); }
  if (tid >= 64 && tid < 128) { sbb1[tid - 64] = ldany(bb1, tid - 64, wf32); sbb2[tid - 64] = ldany(bb2, tid - 64, wf32); }
  if (tid >= 128 && tid < 256) sstats[tid - 128] = g_stats[tid - 128];
  sWb2[tid] = ldany(Wb2, tid, wf32);
  if (tid == 0) sba2 = ldany(ba2, 0, wf32);
  __syncthreads();
  int g = blockIdx.x * 32 + (tid >> 3);     // group = (b,i)
  int j = tid & 7;
  int b = g >> 12, i = g & (S_ - 1);
  int n = i * 8 + j;
  const int* fb = g_idxk + b * 32768;
  int xbase = b * C_ * P_;
  float feat[64];
  elem_vals(x, xf32, xbase, fb, n, sWpos, sbpos, sWconv, sbconv, feat);
#pragma unroll
  for (int c = 0; c < 64; ++c) {
    float v = fmaf(feat[c], sstats[c * 2], sstats[c * 2 + 1]);
    feat[c] = (v >= 0.f) ? v : 0.2f * v;
  }
  float att = sba2;
  for (int h = 0; h < 32; ++h) {
    float acc = sba1[h];
#pragma unroll
    for (int c = 0; c < 64; ++c) acc = fmaf(sWa1[h * 64 + c], feat[c], acc);
    acc = (acc >= 0.f) ? acc : 0.2f * acc;
    att = fmaf(sWa2[h], acc, att);
  }
  float mxv = att;
  for (int mk = 1; mk < 8; mk <<= 1) mxv = fmaxf(mxv, __shfl_xor(mxv, mk, 8));
  float e = expf(att - mxv);
  float se = e;
  for (int mk = 1; mk < 8; mk <<= 1) se += __shfl_xor(se, mk, 8);
  float a = e / se;
#pragma unroll
  for (int c = 0; c < 64; ++c) {
    float w = feat[c] * a;
    w += __shfl_xor(w, 1, 8);
    w += __shfl_xor(w, 2, 8);
    w += __shfl_xor(w, 4, 8);
    feat[c] = w;
  }
  int p0 = fb[i * 8] & (P_ - 1);
  float xc0 = ldany(x, xbase + p0, xf32);
  float xc1 = ldany(x, xbase + P_ + p0, xf32);
  float xc2 = ldany(x, xbase + 2 * P_ + p0, xf32);
  float xc3 = ldany(x, xbase + 3 * P_ + p0, xf32);
  int obase = b * 69 * S_;
#pragma unroll
  for (int oc = 0; oc < 8; ++oc) {
    int o = j * 8 + oc;
    float acc = sbb1[o];
#pragma unroll
    for (int c = 0; c < 64; ++c) acc = fmaf(sWb1[o * 65 + c], feat[c], acc);
    float acc2 = sbb2[o];
    acc2 = fmaf(sWb2[o * 4 + 0], xc0, acc2);
    acc2 = fmaf(sWb2[o * 4 + 1], xc1, acc2);
    acc2 = fmaf(sWb2[o * 4 + 2], xc2, acc2);
    acc2 = fmaf(sWb2[o * 4 + 3], xc3, acc2);
    float r = acc + acc2;
    r = (r >= 0.f) ? r : 0.01f * r;
    int oi = obase + (5 + o) * S_ + i;
    if (xf32) ((float*)out)[oi] = r; else ((u16*)out)[oi] = f2bf(r);
  }
  if (j == 0) {                              // raw pass-through of x1[:, :5, :, 0]
#pragma unroll
    for (int c = 0; c < 5; ++c) {
      int oi = obase + c * S_ + i;
      if (xf32) ((float*)out)[oi] = ((const float*)x)[xbase + c * P_ + p0];
      else      ((u16*)out)[oi]   = ((const u16*)x)[xbase + c * P_ + p0];
    }
  }
}

extern "C" void kernel_launch(void* const* d_in, const int* in_sizes, int n_in,
                              void* d_out, int out_size, void* d_ws, size_t ws_size,
                              hipStream_t stream) {
  const void* x     = d_in[0];
  const void* Wpos  = d_in[1];
  const void* bpos  = d_in[2];
  const void* g2    = d_in[3];
  const void* be2   = d_in[4];
  const void* Wconv = d_in[5];
  const void* bconv = d_in[6];
  const void* g1    = d_in[7];
  const void* be1   = d_in[8];
  const void* Wa1   = d_in[9];
  const void* ba1   = d_in[10];
  const void* Wa2   = d_in[11];
  const void* ba2   = d_in[12];
  const void* Wb1   = d_in[13];
  const void* bb1   = d_in[14];
  const void* Wb2   = d_in[15];
  const void* bb2   = d_in[16];
  (void)d_ws; (void)ws_size; (void)in_sizes; (void)n_in;

  hipLaunchKernelGGL(k_detect, dim3(1), dim3(256), 0, stream,
                     x, Wpos, Wconv, Wa1, Wa2, Wb1, Wb2);
  hipLaunchKernelGGL(k_minmax, dim3(4), dim3(256), 0, stream, x);
  hipLaunchKernelGGL(k_knn1, dim3(B_ * S_), dim3(256), 0, stream, x);
  hipLaunchKernelGGL(k_knn2, dim3(B_ * S_), dim3(256), 0, stream, x);
  hipLaunchKernelGGL(k_partial, dim3(256), dim3(256), 0, stream, x,
                     Wpos, bpos, Wconv, bconv);
  hipLaunchKernelGGL(k_finalize, dim3(1), dim3(64), 0, stream,
                     g1, be1, g2, be2);
  hipLaunchKernelGGL(k_pass2, dim3(256), dim3(256), 0, stream, x,
                     Wpos, bpos, Wconv, bconv, Wa1, ba1, Wa2, ba2,
                     Wb1, bb1, Wb2, bb2, d_out);
}